// Round 1
// baseline (772.461 us; speedup 1.0000x reference)
//
#include <hip/hip_runtime.h>

// ---------------------------------------------------------------------------
// ConvLSTMNet round 8:
//  - lstm: product-major MFMA interleave (4-way chain ILP instead of
//    gate-serial 6-chains), xv prefetch hoisted above the barrier,
//    exp-phase hoisted out of the per-r combine chains, unroll-2 on t
//    to const-fold rb/wb LDS addressing. Bitwise-identical math order.
//  - FC: 2 n-columns per lane (float2 W loads + float2 acc[16]) -> each
//    4x ds_read_b128 A-broadcast now feeds 32 FMAs instead of 16,
//    halving the per-CU LDS-pipe demand that dominates fc2.
// ---------------------------------------------------------------------------

#define T_STEPS 256
#define PIX 55
#define MT 16          // sequences per tile (MFMA N-dim)
#define TILES 110      // 1760 / 16
#define LOG2E 1.4426950408889634f
#define FC_SUB 128     // kc per LDS stage
#define FC_GRP 16      // W pipeline depth

typedef float f32x4 __attribute__((ext_vector_type(4)));
typedef __bf16 bf16x8 __attribute__((ext_vector_type(8)));
typedef __bf16 bf16x4 __attribute__((ext_vector_type(4)));

__global__ __launch_bounds__(256) void lstm_kernel(
    const float* __restrict__ x1, const float* __restrict__ x2,
    const float* __restrict__ wx1, const float* __restrict__ wh1,
    const float* __restrict__ bx1, const float* __restrict__ bh1,
    const float* __restrict__ wx2, const float* __restrict__ wh2,
    const float* __restrict__ bx2, const float* __restrict__ bh2,
    float* __restrict__ feat)   // [64][7040]: row sub*32+b, col (cell*64+u)*55+p
{
    int bid  = blockIdx.x;            // 0..439
    int tile = bid % TILES;
    int cc   = bid / TILES;           // 0..3
    int sub  = cc >> 1, cell = cc & 1;
    const float* x  = sub  ? x2  : x1;
    const float* wx = cell ? wx2 : wx1;
    const float* wh = cell ? wh2 : wh1;
    const float* bx = cell ? bx2 : bx1;
    const float* bh = cell ? bh2 : bh1;

    int tid  = threadIdx.x;
    int w    = tid >> 6;              // wave id = unit subtile (units 16w..16w+15)
    int l    = tid & 63;
    int quad = l >> 4;
    int c16  = l & 15;

    __shared__ float xl[MT * 514];                        // [seq][t*2+c], pad 514
    __shared__ __align__(16) __bf16 hb[2][2][MT][72];     // [buf][hi/lo][seq][u pad72]

    // ---- stage x for this block's 16 sequences (all 256 steps) ----
    {
        int seq0 = tile * MT;
        for (int i = 0; i < 32; ++i) {
            int idx = tid + 256 * i;          // m*512 + t*2 + c
            int m = idx >> 9;
            int tc = idx & 511;
            int t = tc >> 1, c = tc & 1;
            int seq = seq0 + m;
            int b = seq / PIX, p = seq % PIX;
            xl[m * 514 + tc] = x[((b * T_STEPS + t) * 2 + c) * PIX + p];
        }
    }
    // ---- zero h buffers ----
    {
        __bf16* hz = &hb[0][0][0][0];
        for (int i = tid; i < 2 * 2 * MT * 72; i += 256) hz[i] = (__bf16)0.0f;
    }

    // ---- W as A-operand fragments (hi+lo), per gate & K-slab ----
    bf16x8 Whi[4][2], Wlo[4][2];
    float btot[4][4], wxa[4][4], wxb[4][4];
#pragma unroll
    for (int g = 0; g < 4; ++g) {
        int col = 64 * g + 16 * w + c16;
#pragma unroll
        for (int r = 0; r < 4; ++r) {
            int u = 64 * g + 16 * w + 4 * quad + r;   // this thread's C-row units
            btot[g][r] = bx[u] + bh[u];
            wxa[g][r]  = wx[u];
            wxb[g][r]  = wx[256 + u];
        }
#pragma unroll
        for (int q = 0; q < 2; ++q) {
#pragma unroll
            for (int j = 0; j < 8; ++j) {
                int k = 32 * q + 8 * quad + j;
                float wv = wh[k * 256 + col];
                __bf16 hi = (__bf16)wv;
                Whi[g][q][j] = hi;
                Wlo[g][q][j] = (__bf16)(wv - (float)hi);
            }
        }
    }

    float cst[4]  = {0.f, 0.f, 0.f, 0.f};
    float hfin[4] = {0.f, 0.f, 0.f, 0.f};

    // xv for step 0 (xl is read-only after staging; prefetched pre-barrier
    // for every later step)
    __syncthreads();
    float2 xv = *(const float2*)&xl[c16 * 514 + (cell ? (T_STEPS - 1) : 0) * 2];

#pragma unroll 2
    for (int t = 0; t < T_STEPS; ++t) {
        int rb = t & 1, wb = rb ^ 1;

        bf16x8 Bh[2], Bl[2];
#pragma unroll
        for (int q = 0; q < 2; ++q) {
            Bh[q] = *(const bf16x8*)&hb[rb][0][c16][32 * q + 8 * quad];
            Bl[q] = *(const bf16x8*)&hb[rb][1][c16][32 * q + 8 * quad];
        }

        f32x4 acc[4];
#pragma unroll
        for (int g = 0; g < 4; ++g) {
#pragma unroll
            for (int r = 0; r < 4; ++r)
                acc[g][r] = fmaf(xv.y, wxb[g][r], fmaf(xv.x, wxa[g][r], btot[g][r]));
        }
        // product-major: 6 rounds x 4 gates -> 4-way dependent-chain ILP.
        // Per-gate accumulation order identical to gate-major version.
#pragma unroll
        for (int g = 0; g < 4; ++g)
            acc[g] = __builtin_amdgcn_mfma_f32_16x16x32_bf16(Whi[g][0], Bh[0], acc[g], 0, 0, 0);
#pragma unroll
        for (int g = 0; g < 4; ++g)
            acc[g] = __builtin_amdgcn_mfma_f32_16x16x32_bf16(Whi[g][1], Bh[1], acc[g], 0, 0, 0);
#pragma unroll
        for (int g = 0; g < 4; ++g)
            acc[g] = __builtin_amdgcn_mfma_f32_16x16x32_bf16(Wlo[g][0], Bh[0], acc[g], 0, 0, 0);
#pragma unroll
        for (int g = 0; g < 4; ++g)
            acc[g] = __builtin_amdgcn_mfma_f32_16x16x32_bf16(Wlo[g][1], Bh[1], acc[g], 0, 0, 0);
#pragma unroll
        for (int g = 0; g < 4; ++g)
            acc[g] = __builtin_amdgcn_mfma_f32_16x16x32_bf16(Whi[g][0], Bl[0], acc[g], 0, 0, 0);
#pragma unroll
        for (int g = 0; g < 4; ++g)
            acc[g] = __builtin_amdgcn_mfma_f32_16x16x32_bf16(Whi[g][1], Bl[1], acc[g], 0, 0, 0);

        // exp phase: 16 independent transcendentals, streamed
        float ei[4], ef[4], eo[4], eg[4];
#pragma unroll
        for (int r = 0; r < 4; ++r) {
            ei[r] = __builtin_amdgcn_exp2f(-LOG2E * acc[0][r]);
            ef[r] = __builtin_amdgcn_exp2f(-LOG2E * acc[1][r]);
            eo[r] = __builtin_amdgcn_exp2f(-LOG2E * acc[2][r]);
            eg[r] = __builtin_amdgcn_exp2f(-2.0f * LOG2E * acc[3][r]);
        }

        bf16x4 ph, pl;
#pragma unroll
        for (int r = 0; r < 4; ++r) {
            float sf  = __builtin_amdgcn_rcpf(1.0f + ef[r]);
            float itg = (1.0f - eg[r]) * __builtin_amdgcn_rcpf((1.0f + ei[r]) * (1.0f + eg[r]));
            float c   = fmaf(sf, cst[r], itg);
            cst[r] = c;
            float ec = __builtin_amdgcn_exp2f(-2.0f * LOG2E * c);
            float h  = (1.0f - ec) * __builtin_amdgcn_rcpf((1.0f + eo[r]) * (1.0f + ec));
            hfin[r] = h;
            __bf16 hi = (__bf16)h;
            ph[r] = hi;
            pl[r] = (__bf16)(h - (float)hi);
        }
        *(bf16x4*)&hb[wb][0][c16][16 * w + 4 * quad] = ph;
        *(bf16x4*)&hb[wb][1][c16][16 * w + 4 * quad] = pl;

        // prefetch next step's x contribution BEFORE the barrier (xl is
        // read-only; &255 keeps the dead last-iteration index in-bounds)
        {
            int txn = (cell ? (T_STEPS - 2 - t) : (t + 1)) & 255;
            xv = *(const float2*)&xl[c16 * 514 + txn * 2];
        }
        __syncthreads();
    }

    {
        int seq = tile * MT + c16;
        int b = seq / PIX, p = seq % PIX;
#pragma unroll
        for (int r = 0; r < 4; ++r) {
            int u = 16 * w + 4 * quad + r;
            feat[(size_t)(sub * 32 + b) * 7040 + (cell * 64 + u) * PIX + p] = hfin[r];
        }
    }
}

// ---------------------------------------------------------------------------
// FC slim v2: part[split][64][N] = A[64][kchunk] @ W[kchunk][N].
// Block = 64 m x 128 n. Lane owns TWO adjacent n (float2): acc[16] float2 =
// 32 VGPR (still spill-safe). Each 4x ds_read_b128 A-broadcast feeds 32 FMAs
// (2x arithmetic per LDS-pipe cycle vs v1). W: 16-deep float2 pipeline,
// 512 B/wave coalesced. No atomics; fc_reduce sums partials + bias.
// ---------------------------------------------------------------------------
__global__ __launch_bounds__(256) void fc_gemm(const float* __restrict__ A,
                                               const float* __restrict__ W,
                                               float* __restrict__ part,
                                               int K, int N, int kchunk) {
    __shared__ __align__(16) float al[FC_SUB * 68];   // [kc][m pad68]
    int tid = threadIdx.x;
    int l   = tid & 63;
    int wv  = tid >> 6;
    int k0   = blockIdx.y * kchunk;
    int kend = min(K, k0 + kchunk);

    int n  = blockIdx.x * 128 + 2 * l;     // even; lane covers (n, n+1)
    int ne = min(n, N - 2);                // clamped load base (N always even)

    float2 acc[16];
#pragma unroll
    for (int i = 0; i < 16; ++i) acc[i] = make_float2(0.0f, 0.0f);

    for (int ks = k0; ks < kend; ks += FC_SUB) {
        int kcur = min(FC_SUB, kend - ks);
        __syncthreads();                   // protect al reuse
        // ---- stage A[0:64][ks:ks+kcur]: 32 independent coalesced loads ----
        if (kcur == FC_SUB) {
#pragma unroll
            for (int i = 0; i < 32; ++i) {
                int idx = tid + 256 * i;       // m = idx>>7, kc = idx&127
                int m = idx >> 7, kc = idx & 127;
                al[kc * 68 + m] = A[(size_t)m * K + ks + kc];
            }
        } else {
#pragma unroll
            for (int i = 0; i < 32; ++i) {
                int idx = tid + 256 * i;
                int m = idx >> 7, kc = idx & 127;
                if (kc < kcur) al[kc * 68 + m] = A[(size_t)m * K + ks + kc];
            }
        }
        __syncthreads();

        const float* wr = W + (size_t)ks * N + ne;
        int kc0 = 0;
        for (; kc0 + FC_GRP <= kcur; kc0 += FC_GRP) {
            float2 wbuf[FC_GRP];
#pragma unroll
            for (int j = 0; j < FC_GRP; ++j)
                wbuf[j] = *(const float2*)&wr[(size_t)(kc0 + j) * N];  // coalesced 512B
#pragma unroll
            for (int j = 0; j < FC_GRP; ++j) {
                const float4* ap = (const float4*)&al[(kc0 + j) * 68 + 16 * wv];
#pragma unroll
                for (int i = 0; i < 4; ++i) {
                    float4 a = ap[i];
                    acc[4 * i + 0].x = fmaf(a.x, wbuf[j].x, acc[4 * i + 0].x);
                    acc[4 * i + 0].y = fmaf(a.x, wbuf[j].y, acc[4 * i + 0].y);
                    acc[4 * i + 1].x = fmaf(a.y, wbuf[j].x, acc[4 * i + 1].x);
                    acc[4 * i + 1].y = fmaf(a.y, wbuf[j].y, acc[4 * i + 1].y);
                    acc[4 * i + 2].x = fmaf(a.z, wbuf[j].x, acc[4 * i + 2].x);
                    acc[4 * i + 2].y = fmaf(a.z, wbuf[j].y, acc[4 * i + 2].y);
                    acc[4 * i + 3].x = fmaf(a.w, wbuf[j].x, acc[4 * i + 3].x);
                    acc[4 * i + 3].y = fmaf(a.w, wbuf[j].y, acc[4 * i + 3].y);
                }
            }
        }
        for (; kc0 < kcur; ++kc0) {
            float2 wvv = *(const float2*)&wr[(size_t)kc0 * N];
            const float4* ap = (const float4*)&al[kc0 * 68 + 16 * wv];
#pragma unroll
            for (int i = 0; i < 4; ++i) {
                float4 a = ap[i];
                acc[4 * i + 0].x = fmaf(a.x, wvv.x, acc[4 * i + 0].x);
                acc[4 * i + 0].y = fmaf(a.x, wvv.y, acc[4 * i + 0].y);
                acc[4 * i + 1].x = fmaf(a.y, wvv.x, acc[4 * i + 1].x);
                acc[4 * i + 1].y = fmaf(a.y, wvv.y, acc[4 * i + 1].y);
                acc[4 * i + 2].x = fmaf(a.z, wvv.x, acc[4 * i + 2].x);
                acc[4 * i + 2].y = fmaf(a.z, wvv.y, acc[4 * i + 2].y);
                acc[4 * i + 3].x = fmaf(a.w, wvv.x, acc[4 * i + 3].x);
                acc[4 * i + 3].y = fmaf(a.w, wvv.y, acc[4 * i + 3].y);
            }
        }
    }

    if (n < N) {                           // N even, n even -> n+1 < N too
        float* pr = part + (size_t)blockIdx.y * 64 * N + n;
#pragma unroll
        for (int i = 0; i < 16; ++i)
            *(float2*)&pr[(size_t)(16 * wv + i) * N] = acc[i];
    }
}

__global__ __launch_bounds__(256) void fc_reduce(const float* __restrict__ part,
                                                 const float* __restrict__ bias,
                                                 float* __restrict__ out,
                                                 int S, int N) {
    int n = blockIdx.x * 256 + threadIdx.x;
    int m = blockIdx.y;
    if (n >= N) return;
    float s = bias[n];
    for (int i = 0; i < S; ++i)
        s += part[(size_t)i * 64 * N + (size_t)m * N + n];
    out[(size_t)m * N + n] = s;
}

extern "C" void kernel_launch(void* const* d_in, const int* in_sizes, int n_in,
                              void* d_out, int out_size, void* d_ws, size_t ws_size,
                              hipStream_t stream) {
    const float* x1  = (const float*)d_in[0];
    const float* x2  = (const float*)d_in[1];
    const float* wx1 = (const float*)d_in[2];
    const float* wh1 = (const float*)d_in[3];
    const float* bx1 = (const float*)d_in[4];
    const float* bh1 = (const float*)d_in[5];
    const float* wx2 = (const float*)d_in[6];
    const float* wh2 = (const float*)d_in[7];
    const float* bx2 = (const float*)d_in[8];
    const float* bh2 = (const float*)d_in[9];
    const float* fw2 = (const float*)d_in[10];
    const float* fb2 = (const float*)d_in[11];
    const float* fw3 = (const float*)d_in[12];
    const float* fb3 = (const float*)d_in[13];
    const float* fw4 = (const float*)d_in[14];
    const float* fb4 = (const float*)d_in[15];
    const float* fw5 = (const float*)d_in[16];
    const float* fb5 = (const float*)d_in[17];

    char* ws = (char*)d_ws;
    float* feat = (float*)ws;                                   // [64][7040]
    float* t1   = feat + (size_t)64 * 7040;                     // [64][3400]
    float* t2   = t1   + (size_t)64 * 3400;                     // [64][1000]
    float* t3   = t2   + (size_t)64 * 1000;                     // [64][500]
    float* part = t3   + (size_t)64 * 500;                      // up to 27*64*1000 / 14*64*3400
    float* o    = (float*)d_out;                                // [64][50]

    lstm_kernel<<<dim3(440), dim3(256), 0, stream>>>(
        x1, x2, wx1, wh1, bx1, bh1, wx2, wh2, bx2, bh2, feat);

    fc_gemm<<<dim3(27, 14), dim3(256), 0, stream>>>(feat, fw2, part, 7040, 3400, 512);
    fc_reduce<<<dim3(14, 64), dim3(256), 0, stream>>>(part, fb2, t1, 14, 3400);

    fc_gemm<<<dim3(8, 27), dim3(256), 0, stream>>>(t1, fw3, part, 3400, 1000, 128);
    fc_reduce<<<dim3(4, 64), dim3(256), 0, stream>>>(part, fb3, t2, 27, 1000);

    fc_gemm<<<dim3(4, 8), dim3(256), 0, stream>>>(t2, fw4, part, 1000, 500, 128);
    fc_reduce<<<dim3(2, 64), dim3(256), 0, stream>>>(part, fb4, t3, 8, 500);

    fc_gemm<<<dim3(1, 4), dim3(256), 0, stream>>>(t3, fw5, part, 500, 50, 128);
    fc_reduce<<<dim3(1, 64), dim3(256), 0, stream>>>(part, fb5, o, 4, 50);
}

// Round 2
// 581.191 us; speedup vs baseline: 1.3291x; 1.3291x over previous
//
#include <hip/hip_runtime.h>

// ---------------------------------------------------------------------------
// ConvLSTMNet round 9:
//  - lstm: R8 structure (product-major MFMA interleave, xv prefetch, exp
//    hoist, unroll-2) + packed-f32 math: acc-init and the combine phase are
//    written as f32x4 elementwise ops so the backend emits v_pk_fma_f32 /
//    v_pk_add_f32 / v_pk_mul_f32 (same ops, same order -> same numerics,
//    ~half the scalar-VALU issue cycles in those phases).
//  - FC: full revert to the proven R7 "slim" kernels + grids (the R8
//    float2 variant halved block counts and regressed ~200 us).
// ---------------------------------------------------------------------------

#define T_STEPS 256
#define PIX 55
#define MT 16          // sequences per tile (MFMA N-dim)
#define TILES 110      // 1760 / 16
#define LOG2E 1.4426950408889634f
#define FC_SUB 128     // kc per LDS stage
#define FC_GRP 16      // W pipeline depth

typedef float f32x4 __attribute__((ext_vector_type(4)));
typedef __bf16 bf16x8 __attribute__((ext_vector_type(8)));
typedef __bf16 bf16x4 __attribute__((ext_vector_type(4)));

__global__ __launch_bounds__(256) void lstm_kernel(
    const float* __restrict__ x1, const float* __restrict__ x2,
    const float* __restrict__ wx1, const float* __restrict__ wh1,
    const float* __restrict__ bx1, const float* __restrict__ bh1,
    const float* __restrict__ wx2, const float* __restrict__ wh2,
    const float* __restrict__ bx2, const float* __restrict__ bh2,
    float* __restrict__ feat)   // [64][7040]: row sub*32+b, col (cell*64+u)*55+p
{
    int bid  = blockIdx.x;            // 0..439
    int tile = bid % TILES;
    int cc   = bid / TILES;           // 0..3
    int sub  = cc >> 1, cell = cc & 1;
    const float* x  = sub  ? x2  : x1;
    const float* wx = cell ? wx2 : wx1;
    const float* wh = cell ? wh2 : wh1;
    const float* bx = cell ? bx2 : bx1;
    const float* bh = cell ? bh2 : bh1;

    int tid  = threadIdx.x;
    int w    = tid >> 6;              // wave id = unit subtile (units 16w..16w+15)
    int l    = tid & 63;
    int quad = l >> 4;
    int c16  = l & 15;

    __shared__ float xl[MT * 514];                        // [seq][t*2+c], pad 514
    __shared__ __align__(16) __bf16 hb[2][2][MT][72];     // [buf][hi/lo][seq][u pad72]

    // ---- stage x for this block's 16 sequences (all 256 steps) ----
    {
        int seq0 = tile * MT;
        for (int i = 0; i < 32; ++i) {
            int idx = tid + 256 * i;          // m*512 + t*2 + c
            int m = idx >> 9;
            int tc = idx & 511;
            int t = tc >> 1, c = tc & 1;
            int seq = seq0 + m;
            int b = seq / PIX, p = seq % PIX;
            xl[m * 514 + tc] = x[((b * T_STEPS + t) * 2 + c) * PIX + p];
        }
    }
    // ---- zero h buffers ----
    {
        __bf16* hz = &hb[0][0][0][0];
        for (int i = tid; i < 2 * 2 * MT * 72; i += 256) hz[i] = (__bf16)0.0f;
    }

    // ---- W as A-operand fragments (hi+lo), per gate & K-slab ----
    bf16x8 Whi[4][2], Wlo[4][2];
    f32x4 btot4[4], wxa4[4], wxb4[4];
#pragma unroll
    for (int g = 0; g < 4; ++g) {
        int col = 64 * g + 16 * w + c16;
#pragma unroll
        for (int r = 0; r < 4; ++r) {
            int u = 64 * g + 16 * w + 4 * quad + r;   // this thread's C-row units
            btot4[g][r] = bx[u] + bh[u];
            wxa4[g][r]  = wx[u];
            wxb4[g][r]  = wx[256 + u];
        }
#pragma unroll
        for (int q = 0; q < 2; ++q) {
#pragma unroll
            for (int j = 0; j < 8; ++j) {
                int k = 32 * q + 8 * quad + j;
                float wv = wh[k * 256 + col];
                __bf16 hi = (__bf16)wv;
                Whi[g][q][j] = hi;
                Wlo[g][q][j] = (__bf16)(wv - (float)hi);
            }
        }
    }

    f32x4 cst  = {0.f, 0.f, 0.f, 0.f};
    f32x4 hfin = {0.f, 0.f, 0.f, 0.f};

    // xv for step 0 (xl is read-only after staging; prefetched pre-barrier
    // for every later step)
    __syncthreads();
    float2 xv = *(const float2*)&xl[c16 * 514 + (cell ? (T_STEPS - 1) : 0) * 2];

#pragma unroll 2
    for (int t = 0; t < T_STEPS; ++t) {
        int rb = t & 1, wb = rb ^ 1;

        bf16x8 Bh[2], Bl[2];
#pragma unroll
        for (int q = 0; q < 2; ++q) {
            Bh[q] = *(const bf16x8*)&hb[rb][0][c16][32 * q + 8 * quad];
            Bl[q] = *(const bf16x8*)&hb[rb][1][c16][32 * q + 8 * quad];
        }

        // acc init: packed fma (2x v_pk_fma_f32 per gate instead of 8 v_fma)
        f32x4 xx = {xv.x, xv.x, xv.x, xv.x};
        f32x4 yy = {xv.y, xv.y, xv.y, xv.y};
        f32x4 acc[4];
#pragma unroll
        for (int g = 0; g < 4; ++g)
            acc[g] = __builtin_elementwise_fma(
                yy, wxb4[g], __builtin_elementwise_fma(xx, wxa4[g], btot4[g]));

        // product-major: 6 rounds x 4 gates -> 4-way dependent-chain ILP.
#pragma unroll
        for (int g = 0; g < 4; ++g)
            acc[g] = __builtin_amdgcn_mfma_f32_16x16x32_bf16(Whi[g][0], Bh[0], acc[g], 0, 0, 0);
#pragma unroll
        for (int g = 0; g < 4; ++g)
            acc[g] = __builtin_amdgcn_mfma_f32_16x16x32_bf16(Whi[g][1], Bh[1], acc[g], 0, 0, 0);
#pragma unroll
        for (int g = 0; g < 4; ++g)
            acc[g] = __builtin_amdgcn_mfma_f32_16x16x32_bf16(Wlo[g][0], Bh[0], acc[g], 0, 0, 0);
#pragma unroll
        for (int g = 0; g < 4; ++g)
            acc[g] = __builtin_amdgcn_mfma_f32_16x16x32_bf16(Wlo[g][1], Bh[1], acc[g], 0, 0, 0);
#pragma unroll
        for (int g = 0; g < 4; ++g)
            acc[g] = __builtin_amdgcn_mfma_f32_16x16x32_bf16(Whi[g][0], Bl[0], acc[g], 0, 0, 0);
#pragma unroll
        for (int g = 0; g < 4; ++g)
            acc[g] = __builtin_amdgcn_mfma_f32_16x16x32_bf16(Whi[g][1], Bl[1], acc[g], 0, 0, 0);

        // exp phase: packed scale, 20 scalar transcendentals
        f32x4 mi = acc[0] * (-LOG2E);
        f32x4 mf = acc[1] * (-LOG2E);
        f32x4 mo = acc[2] * (-LOG2E);
        f32x4 mg = acc[3] * (-2.0f * LOG2E);
        f32x4 ei4, ef4, eo4, eg4;
#pragma unroll
        for (int r = 0; r < 4; ++r) {
            ei4[r] = __builtin_amdgcn_exp2f(mi[r]);
            ef4[r] = __builtin_amdgcn_exp2f(mf[r]);
            eo4[r] = __builtin_amdgcn_exp2f(mo[r]);
            eg4[r] = __builtin_amdgcn_exp2f(mg[r]);
        }

        // combine: packed adds/muls, scalar rcp
        f32x4 a_ef = 1.0f + ef4;
        f32x4 pig  = (1.0f + ei4) * (1.0f + eg4);
        f32x4 sf4, rig;
#pragma unroll
        for (int r = 0; r < 4; ++r) {
            sf4[r] = __builtin_amdgcn_rcpf(a_ef[r]);
            rig[r] = __builtin_amdgcn_rcpf(pig[r]);
        }
        f32x4 itg = (1.0f - eg4) * rig;
        f32x4 c4  = __builtin_elementwise_fma(sf4, cst, itg);
        cst = c4;

        f32x4 mc = c4 * (-2.0f * LOG2E);
        f32x4 ec4;
#pragma unroll
        for (int r = 0; r < 4; ++r) ec4[r] = __builtin_amdgcn_exp2f(mc[r]);
        f32x4 poc = (1.0f + eo4) * (1.0f + ec4);
        f32x4 roc;
#pragma unroll
        for (int r = 0; r < 4; ++r) roc[r] = __builtin_amdgcn_rcpf(poc[r]);
        f32x4 h4 = (1.0f - ec4) * roc;
        hfin = h4;

        bf16x4 ph, pl;
#pragma unroll
        for (int r = 0; r < 4; ++r) {
            __bf16 hi = (__bf16)h4[r];
            ph[r] = hi;
            pl[r] = (__bf16)(h4[r] - (float)hi);
        }
        *(bf16x4*)&hb[wb][0][c16][16 * w + 4 * quad] = ph;
        *(bf16x4*)&hb[wb][1][c16][16 * w + 4 * quad] = pl;

        // prefetch next step's x contribution BEFORE the barrier (xl is
        // read-only; &255 keeps the dead last-iteration index in-bounds)
        {
            int txn = (cell ? (T_STEPS - 2 - t) : (t + 1)) & 255;
            xv = *(const float2*)&xl[c16 * 514 + txn * 2];
        }
        __syncthreads();
    }

    {
        int seq = tile * MT + c16;
        int b = seq / PIX, p = seq % PIX;
#pragma unroll
        for (int r = 0; r < 4; ++r) {
            int u = 16 * w + 4 * quad + r;
            feat[(size_t)(sub * 32 + b) * 7040 + (cell * 64 + u) * PIX + p] = hfin[r];
        }
    }
}

// ---------------------------------------------------------------------------
// FC slim (R7, proven): part[split][64][N] = A[64][kchunk] @ W[kchunk][N].
// Block = 64 m x 64 n. Lane owns ONE n (acc[16] per wave-m-group = 16 VGPR).
// Wave w -> rows 16w..16w+15 (broadcast b128 A reads). W: 16-deep scalar
// pipeline, coalesced 256 B/wave. A: 32 independent unrolled coalesced loads
// per 128-kc stage. No atomics; fc_reduce sums partials + bias.
// ---------------------------------------------------------------------------
__global__ __launch_bounds__(256) void fc_gemm(const float* __restrict__ A,
                                               const float* __restrict__ W,
                                               float* __restrict__ part,
                                               int K, int N, int kchunk) {
    __shared__ __align__(16) float al[FC_SUB * 68];   // [kc][m pad68]
    int tid = threadIdx.x;
    int l   = tid & 63;
    int wv  = tid >> 6;
    int k0   = blockIdx.y * kchunk;
    int kend = min(K, k0 + kchunk);

    int n  = blockIdx.x * 64 + l;
    int ne = min(n, N - 1);                // clamped load index (stores guarded)

    float acc[16];
#pragma unroll
    for (int i = 0; i < 16; ++i) acc[i] = 0.0f;

    for (int ks = k0; ks < kend; ks += FC_SUB) {
        int kcur = min(FC_SUB, kend - ks);
        __syncthreads();                   // protect al reuse
        // ---- stage A[0:64][ks:ks+kcur]: 32 independent coalesced loads ----
        if (kcur == FC_SUB) {
#pragma unroll
            for (int i = 0; i < 32; ++i) {
                int idx = tid + 256 * i;       // m = idx>>7, kc = idx&127
                int m = idx >> 7, kc = idx & 127;
                al[kc * 68 + m] = A[(size_t)m * K + ks + kc];
            }
        } else {
#pragma unroll
            for (int i = 0; i < 32; ++i) {
                int idx = tid + 256 * i;
                int m = idx >> 7, kc = idx & 127;
                if (kc < kcur) al[kc * 68 + m] = A[(size_t)m * K + ks + kc];
            }
        }
        __syncthreads();

        const float* wr = W + (size_t)ks * N + ne;
        int kc0 = 0;
        for (; kc0 + FC_GRP <= kcur; kc0 += FC_GRP) {
            float wbuf[FC_GRP];
#pragma unroll
            for (int j = 0; j < FC_GRP; ++j)
                wbuf[j] = wr[(size_t)(kc0 + j) * N];    // 16 independent, coalesced
#pragma unroll
            for (int j = 0; j < FC_GRP; ++j) {
                const float4* ap = (const float4*)&al[(kc0 + j) * 68 + 16 * wv];
#pragma unroll
                for (int i = 0; i < 4; ++i) {
                    float4 a = ap[i];
                    acc[4 * i + 0] = fmaf(a.x, wbuf[j], acc[4 * i + 0]);
                    acc[4 * i + 1] = fmaf(a.y, wbuf[j], acc[4 * i + 1]);
                    acc[4 * i + 2] = fmaf(a.z, wbuf[j], acc[4 * i + 2]);
                    acc[4 * i + 3] = fmaf(a.w, wbuf[j], acc[4 * i + 3]);
                }
            }
        }
        for (; kc0 < kcur; ++kc0) {
            float wvv = wr[(size_t)kc0 * N];
            const float4* ap = (const float4*)&al[kc0 * 68 + 16 * wv];
#pragma unroll
            for (int i = 0; i < 4; ++i) {
                float4 a = ap[i];
                acc[4 * i + 0] = fmaf(a.x, wvv, acc[4 * i + 0]);
                acc[4 * i + 1] = fmaf(a.y, wvv, acc[4 * i + 1]);
                acc[4 * i + 2] = fmaf(a.z, wvv, acc[4 * i + 2]);
                acc[4 * i + 3] = fmaf(a.w, wvv, acc[4 * i + 3]);
            }
        }
    }

    if (n < N) {
        float* pr = part + (size_t)blockIdx.y * 64 * N + n;
#pragma unroll
        for (int i = 0; i < 16; ++i)
            pr[(size_t)(16 * wv + i) * N] = acc[i];
    }
}

__global__ __launch_bounds__(256) void fc_reduce(const float* __restrict__ part,
                                                 const float* __restrict__ bias,
                                                 float* __restrict__ out,
                                                 int S, int N) {
    int n = blockIdx.x * 256 + threadIdx.x;
    int m = blockIdx.y;
    if (n >= N) return;
    float s = bias[n];
    for (int i = 0; i < S; ++i)
        s += part[(size_t)i * 64 * N + (size_t)m * N + n];
    out[(size_t)m * N + n] = s;
}

extern "C" void kernel_launch(void* const* d_in, const int* in_sizes, int n_in,
                              void* d_out, int out_size, void* d_ws, size_t ws_size,
                              hipStream_t stream) {
    const float* x1  = (const float*)d_in[0];
    const float* x2  = (const float*)d_in[1];
    const float* wx1 = (const float*)d_in[2];
    const float* wh1 = (const float*)d_in[3];
    const float* bx1 = (const float*)d_in[4];
    const float* bh1 = (const float*)d_in[5];
    const float* wx2 = (const float*)d_in[6];
    const float* wh2 = (const float*)d_in[7];
    const float* bx2 = (const float*)d_in[8];
    const float* bh2 = (const float*)d_in[9];
    const float* fw2 = (const float*)d_in[10];
    const float* fb2 = (const float*)d_in[11];
    const float* fw3 = (const float*)d_in[12];
    const float* fb3 = (const float*)d_in[13];
    const float* fw4 = (const float*)d_in[14];
    const float* fb4 = (const float*)d_in[15];
    const float* fw5 = (const float*)d_in[16];
    const float* fb5 = (const float*)d_in[17];

    char* ws = (char*)d_ws;
    float* feat = (float*)ws;                                   // [64][7040]
    float* t1   = feat + (size_t)64 * 7040;                     // [64][3400]
    float* t2   = t1   + (size_t)64 * 3400;                     // [64][1000]
    float* t3   = t2   + (size_t)64 * 1000;                     // [64][500]
    float* part = t3   + (size_t)64 * 500;                      // up to 27*64*1000 / 14*64*3400
    float* o    = (float*)d_out;                                // [64][50]

    lstm_kernel<<<dim3(440), dim3(256), 0, stream>>>(
        x1, x2, wx1, wh1, bx1, bh1, wx2, wh2, bx2, bh2, feat);

    fc_gemm<<<dim3(54, 14), dim3(256), 0, stream>>>(feat, fw2, part, 7040, 3400, 512);
    fc_reduce<<<dim3(14, 64), dim3(256), 0, stream>>>(part, fb2, t1, 14, 3400);

    fc_gemm<<<dim3(16, 27), dim3(256), 0, stream>>>(t1, fw3, part, 3400, 1000, 128);
    fc_reduce<<<dim3(4, 64), dim3(256), 0, stream>>>(part, fb3, t2, 27, 1000);

    fc_gemm<<<dim3(8, 8), dim3(256), 0, stream>>>(t2, fw4, part, 1000, 500, 128);
    fc_reduce<<<dim3(2, 64), dim3(256), 0, stream>>>(part, fb4, t3, 8, 500);

    fc_gemm<<<dim3(1, 4), dim3(256), 0, stream>>>(t3, fw5, part, 500, 50, 128);
    fc_reduce<<<dim3(1, 64), dim3(256), 0, stream>>>(part, fb5, o, 4, 50);
}

// Round 3
// 550.841 us; speedup vs baseline: 1.4023x; 1.0551x over previous
//
#include <hip/hip_runtime.h>

// ---------------------------------------------------------------------------
// ConvLSTMNet round 10:
//  - lstm: exact R8 revert (best measured 317.8 us, 80 VGPR): product-major
//    MFMA interleave, xv prefetch, exp hoist, unroll-2, scalar combine.
//  - FC: atomic split-K. fc_gemm accumulates into bias-pre-initialized
//    outputs via unsafeAtomicAdd (native global_atomic_add_f32); fc_init
//    (one launch) replaces the four fc_reduce launches. part buffer gone ->
//    split-K no longer ws-capped: fc2 28 splits (1512 blocks, 4 blk/CU at
//    LDS cap), fc3 54, fc4 16, fc5 16. kcur==128 inner loop fully unrolled
//    (8x16 static groups) so the scheduler pipelines W loads across groups.
// ---------------------------------------------------------------------------

#define T_STEPS 256
#define PIX 55
#define MT 16          // sequences per tile (MFMA N-dim)
#define TILES 110      // 1760 / 16
#define LOG2E 1.4426950408889634f
#define FC_SUB 128     // kc per LDS stage
#define FC_GRP 16      // W pipeline depth

typedef float f32x4 __attribute__((ext_vector_type(4)));
typedef __bf16 bf16x8 __attribute__((ext_vector_type(8)));
typedef __bf16 bf16x4 __attribute__((ext_vector_type(4)));

__global__ __launch_bounds__(256) void lstm_kernel(
    const float* __restrict__ x1, const float* __restrict__ x2,
    const float* __restrict__ wx1, const float* __restrict__ wh1,
    const float* __restrict__ bx1, const float* __restrict__ bh1,
    const float* __restrict__ wx2, const float* __restrict__ wh2,
    const float* __restrict__ bx2, const float* __restrict__ bh2,
    float* __restrict__ feat)   // [64][7040]: row sub*32+b, col (cell*64+u)*55+p
{
    int bid  = blockIdx.x;            // 0..439
    int tile = bid % TILES;
    int cc   = bid / TILES;           // 0..3
    int sub  = cc >> 1, cell = cc & 1;
    const float* x  = sub  ? x2  : x1;
    const float* wx = cell ? wx2 : wx1;
    const float* wh = cell ? wh2 : wh1;
    const float* bx = cell ? bx2 : bx1;
    const float* bh = cell ? bh2 : bh1;

    int tid  = threadIdx.x;
    int w    = tid >> 6;              // wave id = unit subtile (units 16w..16w+15)
    int l    = tid & 63;
    int quad = l >> 4;
    int c16  = l & 15;

    __shared__ float xl[MT * 514];                        // [seq][t*2+c], pad 514
    __shared__ __align__(16) __bf16 hb[2][2][MT][72];     // [buf][hi/lo][seq][u pad72]

    // ---- stage x for this block's 16 sequences (all 256 steps) ----
    {
        int seq0 = tile * MT;
        for (int i = 0; i < 32; ++i) {
            int idx = tid + 256 * i;          // m*512 + t*2 + c
            int m = idx >> 9;
            int tc = idx & 511;
            int t = tc >> 1, c = tc & 1;
            int seq = seq0 + m;
            int b = seq / PIX, p = seq % PIX;
            xl[m * 514 + tc] = x[((b * T_STEPS + t) * 2 + c) * PIX + p];
        }
    }
    // ---- zero h buffers ----
    {
        __bf16* hz = &hb[0][0][0][0];
        for (int i = tid; i < 2 * 2 * MT * 72; i += 256) hz[i] = (__bf16)0.0f;
    }

    // ---- W as A-operand fragments (hi+lo), per gate & K-slab ----
    bf16x8 Whi[4][2], Wlo[4][2];
    float btot[4][4], wxa[4][4], wxb[4][4];
#pragma unroll
    for (int g = 0; g < 4; ++g) {
        int col = 64 * g + 16 * w + c16;
#pragma unroll
        for (int r = 0; r < 4; ++r) {
            int u = 64 * g + 16 * w + 4 * quad + r;   // this thread's C-row units
            btot[g][r] = bx[u] + bh[u];
            wxa[g][r]  = wx[u];
            wxb[g][r]  = wx[256 + u];
        }
#pragma unroll
        for (int q = 0; q < 2; ++q) {
#pragma unroll
            for (int j = 0; j < 8; ++j) {
                int k = 32 * q + 8 * quad + j;
                float wv = wh[k * 256 + col];
                __bf16 hi = (__bf16)wv;
                Whi[g][q][j] = hi;
                Wlo[g][q][j] = (__bf16)(wv - (float)hi);
            }
        }
    }

    float cst[4]  = {0.f, 0.f, 0.f, 0.f};
    float hfin[4] = {0.f, 0.f, 0.f, 0.f};

    // xv for step 0 (xl is read-only after staging; prefetched pre-barrier
    // for every later step)
    __syncthreads();
    float2 xv = *(const float2*)&xl[c16 * 514 + (cell ? (T_STEPS - 1) : 0) * 2];

#pragma unroll 2
    for (int t = 0; t < T_STEPS; ++t) {
        int rb = t & 1, wb = rb ^ 1;

        bf16x8 Bh[2], Bl[2];
#pragma unroll
        for (int q = 0; q < 2; ++q) {
            Bh[q] = *(const bf16x8*)&hb[rb][0][c16][32 * q + 8 * quad];
            Bl[q] = *(const bf16x8*)&hb[rb][1][c16][32 * q + 8 * quad];
        }

        f32x4 acc[4];
#pragma unroll
        for (int g = 0; g < 4; ++g) {
#pragma unroll
            for (int r = 0; r < 4; ++r)
                acc[g][r] = fmaf(xv.y, wxb[g][r], fmaf(xv.x, wxa[g][r], btot[g][r]));
        }
        // product-major: 6 rounds x 4 gates -> 4-way dependent-chain ILP.
#pragma unroll
        for (int g = 0; g < 4; ++g)
            acc[g] = __builtin_amdgcn_mfma_f32_16x16x32_bf16(Whi[g][0], Bh[0], acc[g], 0, 0, 0);
#pragma unroll
        for (int g = 0; g < 4; ++g)
            acc[g] = __builtin_amdgcn_mfma_f32_16x16x32_bf16(Whi[g][1], Bh[1], acc[g], 0, 0, 0);
#pragma unroll
        for (int g = 0; g < 4; ++g)
            acc[g] = __builtin_amdgcn_mfma_f32_16x16x32_bf16(Wlo[g][0], Bh[0], acc[g], 0, 0, 0);
#pragma unroll
        for (int g = 0; g < 4; ++g)
            acc[g] = __builtin_amdgcn_mfma_f32_16x16x32_bf16(Wlo[g][1], Bh[1], acc[g], 0, 0, 0);
#pragma unroll
        for (int g = 0; g < 4; ++g)
            acc[g] = __builtin_amdgcn_mfma_f32_16x16x32_bf16(Whi[g][0], Bl[0], acc[g], 0, 0, 0);
#pragma unroll
        for (int g = 0; g < 4; ++g)
            acc[g] = __builtin_amdgcn_mfma_f32_16x16x32_bf16(Whi[g][1], Bl[1], acc[g], 0, 0, 0);

        // exp phase: 16 independent transcendentals, streamed
        float ei[4], ef[4], eo[4], eg[4];
#pragma unroll
        for (int r = 0; r < 4; ++r) {
            ei[r] = __builtin_amdgcn_exp2f(-LOG2E * acc[0][r]);
            ef[r] = __builtin_amdgcn_exp2f(-LOG2E * acc[1][r]);
            eo[r] = __builtin_amdgcn_exp2f(-LOG2E * acc[2][r]);
            eg[r] = __builtin_amdgcn_exp2f(-2.0f * LOG2E * acc[3][r]);
        }

        bf16x4 ph, pl;
#pragma unroll
        for (int r = 0; r < 4; ++r) {
            float sf  = __builtin_amdgcn_rcpf(1.0f + ef[r]);
            float itg = (1.0f - eg[r]) * __builtin_amdgcn_rcpf((1.0f + ei[r]) * (1.0f + eg[r]));
            float c   = fmaf(sf, cst[r], itg);
            cst[r] = c;
            float ec = __builtin_amdgcn_exp2f(-2.0f * LOG2E * c);
            float h  = (1.0f - ec) * __builtin_amdgcn_rcpf((1.0f + eo[r]) * (1.0f + ec));
            hfin[r] = h;
            __bf16 hi = (__bf16)h;
            ph[r] = hi;
            pl[r] = (__bf16)(h - (float)hi);
        }
        *(bf16x4*)&hb[wb][0][c16][16 * w + 4 * quad] = ph;
        *(bf16x4*)&hb[wb][1][c16][16 * w + 4 * quad] = pl;

        // prefetch next step's x contribution BEFORE the barrier (xl is
        // read-only; &255 keeps the dead last-iteration index in-bounds)
        {
            int txn = (cell ? (T_STEPS - 2 - t) : (t + 1)) & 255;
            xv = *(const float2*)&xl[c16 * 514 + txn * 2];
        }
        __syncthreads();
    }

    {
        int seq = tile * MT + c16;
        int b = seq / PIX, p = seq % PIX;
#pragma unroll
        for (int r = 0; r < 4; ++r) {
            int u = 16 * w + 4 * quad + r;
            feat[(size_t)(sub * 32 + b) * 7040 + (cell * 64 + u) * PIX + p] = hfin[r];
        }
    }
}

// ---------------------------------------------------------------------------
// fc_init: pre-fill all four FC outputs with their bias rows (replaces the
// four fc_reduce launches; fc_gemm then accumulates atomically).
// Layout: t1[64][3400], t2[64][1000], t3[64][500], o[64][50].
// ---------------------------------------------------------------------------
__global__ __launch_bounds__(256) void fc_init(
    const float* __restrict__ b2, const float* __restrict__ b3,
    const float* __restrict__ b4, const float* __restrict__ b5,
    float* __restrict__ t1, float* __restrict__ t2,
    float* __restrict__ t3, float* __restrict__ o)
{
    int i = blockIdx.x * 256 + threadIdx.x;
    const int n1 = 64 * 3400, n2 = 64 * 1000, n3 = 64 * 500, n4 = 64 * 50;
    if (i < n1) { t1[i] = b2[i % 3400]; return; }
    i -= n1;
    if (i < n2) { t2[i] = b3[i % 1000]; return; }
    i -= n2;
    if (i < n3) { t3[i] = b4[i % 500]; return; }
    i -= n3;
    if (i < n4) { o[i] = b5[i % 50]; }
}

// ---------------------------------------------------------------------------
// FC slim v3 (atomic split-K): out[64][N] += A[64][kchunk] @ W[kchunk][N].
// Block = 64 m x 64 n. Lane owns ONE n (acc[16] = 16 VGPR). Wave w -> rows
// 16w..16w+15 (broadcast b128 A reads). kcur==128 path fully unrolled (8x16
// static groups -> scheduler pipelines W loads across groups). Accumulation
// into bias-pre-initialized out via native f32 atomics.
// ---------------------------------------------------------------------------
__global__ __launch_bounds__(256) void fc_gemm(const float* __restrict__ A,
                                               const float* __restrict__ W,
                                               float* __restrict__ out,
                                               int K, int N, int kchunk) {
    __shared__ __align__(16) float al[FC_SUB * 68];   // [kc][m pad68]
    int tid = threadIdx.x;
    int l   = tid & 63;
    int wv  = tid >> 6;
    int k0   = blockIdx.y * kchunk;
    int kend = min(K, k0 + kchunk);

    int n  = blockIdx.x * 64 + l;
    int ne = min(n, N - 1);                // clamped load index (stores guarded)

    float acc[16];
#pragma unroll
    for (int i = 0; i < 16; ++i) acc[i] = 0.0f;

    for (int ks = k0; ks < kend; ks += FC_SUB) {
        int kcur = min(FC_SUB, kend - ks);
        __syncthreads();                   // protect al reuse
        // ---- stage A[0:64][ks:ks+kcur]: 32 independent coalesced loads ----
        if (kcur == FC_SUB) {
#pragma unroll
            for (int i = 0; i < 32; ++i) {
                int idx = tid + 256 * i;       // m = idx>>7, kc = idx&127
                int m = idx >> 7, kc = idx & 127;
                al[kc * 68 + m] = A[(size_t)m * K + ks + kc];
            }
        } else {
#pragma unroll
            for (int i = 0; i < 32; ++i) {
                int idx = tid + 256 * i;
                int m = idx >> 7, kc = idx & 127;
                if (kc < kcur) al[kc * 68 + m] = A[(size_t)m * K + ks + kc];
            }
        }
        __syncthreads();

        const float* wr = W + (size_t)ks * N + ne;
        if (kcur == FC_SUB) {
            // hot path: 8 static groups of 16, fully unrolled
#pragma unroll
            for (int g8 = 0; g8 < FC_SUB / FC_GRP; ++g8) {
                float wbuf[FC_GRP];
#pragma unroll
                for (int j = 0; j < FC_GRP; ++j)
                    wbuf[j] = wr[(size_t)(g8 * FC_GRP + j) * N];
#pragma unroll
                for (int j = 0; j < FC_GRP; ++j) {
                    const float4* ap = (const float4*)&al[(g8 * FC_GRP + j) * 68 + 16 * wv];
#pragma unroll
                    for (int i = 0; i < 4; ++i) {
                        float4 a = ap[i];
                        acc[4 * i + 0] = fmaf(a.x, wbuf[j], acc[4 * i + 0]);
                        acc[4 * i + 1] = fmaf(a.y, wbuf[j], acc[4 * i + 1]);
                        acc[4 * i + 2] = fmaf(a.z, wbuf[j], acc[4 * i + 2]);
                        acc[4 * i + 3] = fmaf(a.w, wbuf[j], acc[4 * i + 3]);
                    }
                }
            }
        } else {
            int kc0 = 0;
            for (; kc0 + FC_GRP <= kcur; kc0 += FC_GRP) {
                float wbuf[FC_GRP];
#pragma unroll
                for (int j = 0; j < FC_GRP; ++j)
                    wbuf[j] = wr[(size_t)(kc0 + j) * N];
#pragma unroll
                for (int j = 0; j < FC_GRP; ++j) {
                    const float4* ap = (const float4*)&al[(kc0 + j) * 68 + 16 * wv];
#pragma unroll
                    for (int i = 0; i < 4; ++i) {
                        float4 a = ap[i];
                        acc[4 * i + 0] = fmaf(a.x, wbuf[j], acc[4 * i + 0]);
                        acc[4 * i + 1] = fmaf(a.y, wbuf[j], acc[4 * i + 1]);
                        acc[4 * i + 2] = fmaf(a.z, wbuf[j], acc[4 * i + 2]);
                        acc[4 * i + 3] = fmaf(a.w, wbuf[j], acc[4 * i + 3]);
                    }
                }
            }
            for (; kc0 < kcur; ++kc0) {
                float wvv = wr[(size_t)kc0 * N];
                const float4* ap = (const float4*)&al[kc0 * 68 + 16 * wv];
#pragma unroll
                for (int i = 0; i < 4; ++i) {
                    float4 a = ap[i];
                    acc[4 * i + 0] = fmaf(a.x, wvv, acc[4 * i + 0]);
                    acc[4 * i + 1] = fmaf(a.y, wvv, acc[4 * i + 1]);
                    acc[4 * i + 2] = fmaf(a.z, wvv, acc[4 * i + 2]);
                    acc[4 * i + 3] = fmaf(a.w, wvv, acc[4 * i + 3]);
                }
            }
        }
    }

    if (n < N) {
        float* pr = out + n;
#pragma unroll
        for (int i = 0; i < 16; ++i)
            unsafeAtomicAdd(&pr[(size_t)(16 * wv + i) * N], acc[i]);
    }
}

extern "C" void kernel_launch(void* const* d_in, const int* in_sizes, int n_in,
                              void* d_out, int out_size, void* d_ws, size_t ws_size,
                              hipStream_t stream) {
    const float* x1  = (const float*)d_in[0];
    const float* x2  = (const float*)d_in[1];
    const float* wx1 = (const float*)d_in[2];
    const float* wh1 = (const float*)d_in[3];
    const float* bx1 = (const float*)d_in[4];
    const float* bh1 = (const float*)d_in[5];
    const float* wx2 = (const float*)d_in[6];
    const float* wh2 = (const float*)d_in[7];
    const float* bx2 = (const float*)d_in[8];
    const float* bh2 = (const float*)d_in[9];
    const float* fw2 = (const float*)d_in[10];
    const float* fb2 = (const float*)d_in[11];
    const float* fw3 = (const float*)d_in[12];
    const float* fb3 = (const float*)d_in[13];
    const float* fw4 = (const float*)d_in[14];
    const float* fb4 = (const float*)d_in[15];
    const float* fw5 = (const float*)d_in[16];
    const float* fb5 = (const float*)d_in[17];

    char* ws = (char*)d_ws;
    float* feat = (float*)ws;                                   // [64][7040]
    float* t1   = feat + (size_t)64 * 7040;                     // [64][3400]
    float* t2   = t1   + (size_t)64 * 3400;                     // [64][1000]
    float* t3   = t2   + (size_t)64 * 1000;                     // [64][500]
    float* o    = (float*)d_out;                                // [64][50]

    // bias pre-fill for all four FC outputs (316800 elems)
    fc_init<<<dim3(1238), dim3(256), 0, stream>>>(fb2, fb3, fb4, fb5, t1, t2, t3, o);

    lstm_kernel<<<dim3(440), dim3(256), 0, stream>>>(
        x1, x2, wx1, wh1, bx1, bh1, wx2, wh2, bx2, bh2, feat);

    // atomic split-K GEMMs (out pre-filled with bias)
    fc_gemm<<<dim3(54, 28), dim3(256), 0, stream>>>(feat, fw2, t1, 7040, 3400, 256);
    fc_gemm<<<dim3(16, 54), dim3(256), 0, stream>>>(t1, fw3, t2, 3400, 1000, 64);
    fc_gemm<<<dim3(8, 16), dim3(256), 0, stream>>>(t2, fw4, t3, 1000, 500, 64);
    fc_gemm<<<dim3(1, 16), dim3(256), 0, stream>>>(t3, fw5, o, 500, 50, 32);
}